// Round 1
// 165.341 us; speedup vs baseline: 1.0515x; 1.0515x over previous
//
#include <hip/hip_runtime.h>
#include <math.h>

#define HDIM 256
#define PDIM 256
#define BATCH 8
#define LSEQ 4096
#define MTOT (BATCH * LSEQ)   // 32768
#define NCHUNK 128
#define CHLEN 32              // NCHUNK*CHLEN == LSEQ

typedef __attribute__((ext_vector_type(8))) short bf16x8;   // 8 bf16 = 4 VGPRs
typedef __attribute__((ext_vector_type(4))) float f32x4;

__device__ __forceinline__ unsigned short f2bf(float f) {
    union { float f; unsigned int u; } v; v.f = f;
    unsigned int r = v.u + 0x7FFFu + ((v.u >> 16) & 1u);   // RNE
    return (unsigned short)(r >> 16);
}
__device__ __forceinline__ float bf2f(unsigned int lo16) {
    union { unsigned int u; float f; } v; v.u = lo16 << 16;
    return v.f;
}

// async global->LDS, 16B per lane; LDS dest is wave-uniform base + lane*16
__device__ __forceinline__ void gload_lds16(const void* g, void* l) {
    __builtin_amdgcn_global_load_lds(
        (const __attribute__((address_space(1))) void*)g,
        (__attribute__((address_space(3))) void*)l, 16, 0, 0);
}

// ---------------- param precompute: a, coef=(a-1)/lam, a^CHLEN ----------------
// par floats: [0:512) a  [512:1024) coef  [1024:1536) a^CHLEN  (interleaved r,i)
__global__ void params_k(const float* __restrict__ llr, const float* __restrict__ lim,
                         const float* __restrict__ ldl, float* __restrict__ par) {
    int p = threadIdx.x;
    float er = expf(llr[p]);          // -Re(lam) > 0
    float im = lim[p];
    float d  = expf(ldl[p]);
    float zr = -er * d, zi = im * d;  // lam*delta
    float ea = expf(zr);
    float ar = ea * cosf(zi), ai = ea * sinf(zi);   // a = exp(lam*delta)
    float dr = -er, di = im;
    float den = dr * dr + di * di;
    float nr = ar - 1.0f, ni = ai;
    float cr = (nr * dr + ni * di) / den;           // coef = (a-1)/lam
    float ci = (ni * dr - nr * di) / den;
    float eC = expf((float)CHLEN * zr);
    float sC, cC;
    sincosf((float)CHLEN * zi, &sC, &cC);
    par[2 * p]           = ar;
    par[2 * p + 1]       = ai;
    par[512 + 2 * p]     = cr;
    par[512 + 2 * p + 1] = ci;
    par[1024 + 2 * p]     = eC * cC;
    par[1024 + 2 * p + 1] = eC * sC;
}

// merged W1t/W2t build (one launch; w1-half recomputes coef locally so it
// doesn't depend on params_k)
// W1t[n][k]: n=2p -> Re(coef_p * B_tilde[p][k]); n=2p+1 -> Im. (bf16, [512][256])
// W2t[h][2p] = Cr[h][p]; W2t[h][2p+1] = -Ci[h][p]. (bf16, [256][512])
__global__ void wpack_k(const float* __restrict__ llr, const float* __restrict__ lim,
                        const float* __restrict__ ldl,
                        const float* __restrict__ Br, const float* __restrict__ Bi,
                        const float* __restrict__ Cr, const float* __restrict__ Ci,
                        unsigned short* __restrict__ W1t, unsigned short* __restrict__ W2t) {
    int h = threadIdx.x;
    if (blockIdx.x < PDIM) {
        int p = blockIdx.x;
        float er = expf(llr[p]);
        float im = lim[p];
        float d  = expf(ldl[p]);
        float zr = -er * d, zi = im * d;
        float ea = expf(zr);
        float sz, cz; sincosf(zi, &sz, &cz);
        float ar = ea * cz, ai = ea * sz;
        float dr = -er, di = im;
        float den = dr * dr + di * di;
        float nr = ar - 1.0f, ni = ai;
        float cr = (nr * dr + ni * di) / den;
        float ci = (ni * dr - nr * di) / den;
        float br = Br[p * HDIM + h], bi = Bi[p * HDIM + h];
        W1t[(2 * p) * HDIM + h]     = f2bf(cr * br - ci * bi);
        W1t[(2 * p + 1) * HDIM + h] = f2bf(cr * bi + ci * br);
    } else {
        int p = blockIdx.x - PDIM;
        W2t[h * (2 * PDIM) + 2 * p]     = f2bf(Cr[h * PDIM + p]);
        W2t[h * (2 * PDIM) + 2 * p + 1] = f2bf(-Ci[h * PDIM + p]);
    }
}

// ---------------- fused LayerNorm -> bf16 h ----------------
__global__ void ln_k(const float* __restrict__ u, unsigned short* __restrict__ hbf,
                     const float* __restrict__ gamma, const float* __restrict__ beta) {
    __shared__ float gS[HDIM], bS[HDIM];
    int t = threadIdx.x;
    gS[t] = gamma[t]; bS[t] = beta[t];
    int lane = t & 63, wv = t >> 6;
    int row = blockIdx.x * 4 + wv;
    float4 v = *(const float4*)(u + (size_t)row * HDIM + lane * 4);
    float s  = v.x + v.y + v.z + v.w;
    float sq = v.x * v.x + v.y * v.y + v.z * v.z + v.w * v.w;
    #pragma unroll
    for (int o = 1; o < 64; o <<= 1) { s += __shfl_xor(s, o); sq += __shfl_xor(sq, o); }
    float mu = s * (1.0f / HDIM);
    float rs = rsqrtf(sq * (1.0f / HDIM) - mu * mu + 1e-5f);
    __syncthreads();
    int c = lane * 4;
    ushort4 o;
    o.x = f2bf((v.x - mu) * rs * gS[c + 0] + bS[c + 0]);
    o.y = f2bf((v.y - mu) * rs * gS[c + 1] + bS[c + 1]);
    o.z = f2bf((v.z - mu) * rs * gS[c + 2] + bS[c + 2]);
    o.w = f2bf((v.w - mu) * rs * gS[c + 3] + bS[c + 3]);
    *(ushort4*)(hbf + (size_t)row * HDIM + c) = o;
}

// ---------------- bf16 MFMA GEMM: C[M][N] = A[M][K] * Bt[N][K] ----------------
// m97 structure: 128x128 tile, BK=32, linear LDS [128][32] staged via
// global_load_lds width-16 (2 instrs/operand/wave), 2 barriers per k-step.
// Bank-conflict fix (rule #21: both-sides involution): LDS slot (row, cs)
// holds global 16B-chunk (cs ^ ((row>>1)&3)); reads apply the same XOR.
// Wave w stages rows 32w..32w+31 of both tiles (lane -> row 32w+16i+(l>>2),
// slot l&3; global chunk = (l&3)^((l>>3)&3) which equals slot^((row>>1)&3)).
// XCD-chunked block remap: bn-siblings that share an A-panel land on the
// same XCD L2 (nwg%8==0 for both launches -> bijective).
// MODE 0: store bf16. MODE 1: out fp32 = u + gelu(acc).
template <int MODE, int K>
__launch_bounds__(256, 2)
__global__ void mfma_gemm_k(const unsigned short* __restrict__ A,
                            const unsigned short* __restrict__ B,
                            void* __restrict__ outv,
                            const float* __restrict__ u,
                            int N) {
    __shared__ __align__(16) unsigned short As[128 * 32];
    __shared__ __align__(16) unsigned short Bs[128 * 32];
    const int t = threadIdx.x;

    // XCD-aware remap (8 XCDs, hw round-robins blockIdx across XCDs)
    const int nbn  = (int)gridDim.x;
    const int flat = (int)blockIdx.y * nbn + (int)blockIdx.x;
    const int nwg  = nbn * (int)gridDim.y;
    const int tile = (flat & 7) * (nwg >> 3) + (flat >> 3);
    const int bn = tile % nbn, bm = tile / nbn;

    const int lane = t & 63, w = t >> 6;

    // staging addresses (constant over k-loop except +k0)
    const int srow   = 32 * w + (lane >> 2);
    const int schunk = (lane & 3) ^ ((lane >> 3) & 3);
    const unsigned short* gA = A + (size_t)(bm * 128 + srow) * K + schunk * 8;
    const unsigned short* gB = B + (size_t)(bn * 128 + srow) * K + schunk * 8;
    unsigned short* lA0 = &As[(32 * w) * 32];
    unsigned short* lA1 = &As[(32 * w + 16) * 32];
    unsigned short* lB0 = &Bs[(32 * w) * 32];
    unsigned short* lB1 = &Bs[(32 * w + 16) * 32];

    const int wm = (w & 1) * 64;
    const int wn = (w >> 1) * 64;
    const int mrow = lane & 15;
    const int rsw  = (mrow >> 1) & 3;          // == (row>>1)&3 for all fragment rows
    const int cch  = lane >> 4;                // k-chunk this lane group reads
    const int fcol = ((cch ^ rsw) * 8);        // swizzled element offset in row

    f32x4 acc[4][4] = {};

    for (int k0 = 0; k0 < K; k0 += 32) {
        __syncthreads();                       // previous tile fully consumed
        gload_lds16(gA + k0,          lA0);
        gload_lds16(gA + 16 * K + k0, lA1);
        gload_lds16(gB + k0,          lB0);
        gload_lds16(gB + 16 * K + k0, lB1);
        __syncthreads();                       // compiler drains vmcnt before barrier
        bf16x8 fa[4], fb[4];
        #pragma unroll
        for (int i = 0; i < 4; i++) {
            fa[i] = *(const bf16x8*)&As[(wm + i * 16 + mrow) * 32 + fcol];
            fb[i] = *(const bf16x8*)&Bs[(wn + i * 16 + mrow) * 32 + fcol];
        }
        #pragma unroll
        for (int i = 0; i < 4; i++)
            #pragma unroll
            for (int j = 0; j < 4; j++)
                acc[i][j] = __builtin_amdgcn_mfma_f32_16x16x32_bf16(fa[i], fb[j], acc[i][j], 0, 0, 0);
    }

    // C/D layout (m89-verified): col = lane&15, row = (lane>>4)*4 + reg
    const int r0 = (lane >> 4) * 4;
    const int c0 = lane & 15;
    #pragma unroll
    for (int i = 0; i < 4; i++) {
        #pragma unroll
        for (int r = 0; r < 4; r++) {
            const size_t rowoff = (size_t)(bm * 128 + wm + i * 16 + r0 + r) * N;
            #pragma unroll
            for (int j = 0; j < 4; j++) {
                const int col_g = bn * 128 + wn + j * 16 + c0;
                float y = acc[i][j][r];
                if (MODE == 0) {
                    ((unsigned short*)outv)[rowoff + col_g] = f2bf(y);
                } else {
                    float z = 0.7978845608f * fmaf(0.044715f * y * y, y, y);
                    float e = __expf(2.0f * z);
                    float th = 1.0f - 2.0f / (e + 1.0f);
                    float g = 0.5f * y * (1.0f + th);
                    ((float*)outv)[rowoff + col_g] = u[rowoff + col_g] + g;
                }
            }
        }
    }
}

// ---------------- chunked diagonal complex scan over bf16 Bu ----------------
// pass 1: per-(chunk,batch) block, thread=p: chunk-local reduction (no writes to Bu)
__global__ void scan_reduce_k(const unsigned short* __restrict__ Bu,
                              const float* __restrict__ par, float* __restrict__ last) {
    int p = threadIdx.x, c = blockIdx.x, b = blockIdx.y;
    float ar = par[2 * p], ai = par[2 * p + 1];
    float xr = 0.0f, xi = 0.0f;
    const unsigned int* q = (const unsigned int*)(Bu + ((size_t)b * LSEQ + (size_t)c * CHLEN) * 512) + p;
    #pragma unroll 8
    for (int j = 0; j < CHLEN; j++) {
        unsigned int v = q[j * 256];
        float vr = bf2f(v & 0xFFFFu), vi = bf2f(v >> 16);
        float nr = fmaf(ar, xr, fmaf(-ai, xi, vr));
        float ni = fmaf(ar, xi, fmaf(ai, xr, vi));
        xr = nr; xi = ni;
    }
    *(float2*)(last + ((size_t)b * NCHUNK + c) * 512 + 2 * p) = make_float2(xr, xi);
}

// pass 2: per-(b,p) sequential carry across chunks; prefix[c] = state entering chunk c
// software-prefetch in batches of 16 so the dependent chain never waits on HBM/L2
__global__ void scan_carry_k(const float* __restrict__ last, float* __restrict__ prefix,
                             const float* __restrict__ par) {
    int p = threadIdx.x, b = blockIdx.x;
    float Ar = par[1024 + 2 * p], Ai = par[1024 + 2 * p + 1];  // a^CHLEN
    float Pr = 0.0f, Pi = 0.0f;
    const float2* lp = (const float2*)(last + (size_t)b * NCHUNK * 512) + p;
    float2* pp = (float2*)(prefix + (size_t)b * NCHUNK * 512) + p;
    for (int c0 = 0; c0 < NCHUNK; c0 += 16) {
        float2 v[16];
        #pragma unroll
        for (int j = 0; j < 16; j++) v[j] = lp[(size_t)(c0 + j) * 256];
        #pragma unroll
        for (int j = 0; j < 16; j++) {
            pp[(size_t)(c0 + j) * 256] = make_float2(Pr, Pi);
            float nr = fmaf(Ar, Pr, fmaf(-Ai, Pi, v[j].x));
            float ni = fmaf(Ar, Pi, fmaf(Ai, Pr, v[j].y));
            Pr = nr; Pi = ni;
        }
    }
}

// pass 3: redo local recursion seeded with prefix, overwrite Bu with x (bf16)
__global__ void scan_apply_k(unsigned short* __restrict__ Bu, const float* __restrict__ par,
                             const float* __restrict__ prefix) {
    int p = threadIdx.x, c = blockIdx.x, b = blockIdx.y;
    float ar = par[2 * p], ai = par[2 * p + 1];
    float2 P = *(const float2*)(prefix + ((size_t)b * NCHUNK + c) * 512 + 2 * p);
    float xr = P.x, xi = P.y;
    unsigned int* q = (unsigned int*)(Bu + ((size_t)b * LSEQ + (size_t)c * CHLEN) * 512) + p;
    #pragma unroll 8
    for (int j = 0; j < CHLEN; j++) {
        unsigned int v = q[j * 256];
        float vr = bf2f(v & 0xFFFFu), vi = bf2f(v >> 16);
        float nr = fmaf(ar, xr, fmaf(-ai, xi, vr));
        float ni = fmaf(ar, xi, fmaf(ai, xr, vi));
        xr = nr; xi = ni;
        q[j * 256] = (unsigned int)f2bf(xr) | ((unsigned int)f2bf(xi) << 16);
    }
}

extern "C" void kernel_launch(void* const* d_in, const int* in_sizes, int n_in,
                              void* d_out, int out_size, void* d_ws, size_t ws_size,
                              hipStream_t stream) {
    const float* u   = (const float*)d_in[0];
    const float* llr = (const float*)d_in[1];
    const float* lim = (const float*)d_in[2];
    const float* Br  = (const float*)d_in[3];
    const float* Bi  = (const float*)d_in[4];
    const float* Cr  = (const float*)d_in[5];
    const float* Ci  = (const float*)d_in[6];
    const float* ldl = (const float*)d_in[7];
    const float* gam = (const float*)d_in[8];
    const float* bet = (const float*)d_in[9];
    float* out = (float*)d_out;

    float* ws     = (float*)d_ws;
    float* par    = ws;                                     // 2048 floats
    float* last   = ws + 2048;                              // 8*128*512 floats (2 MB)
    float* prefix = last + (size_t)BATCH * NCHUNK * 512;    // 2 MB
    unsigned short* W1t = (unsigned short*)(prefix + (size_t)BATCH * NCHUNK * 512);
    unsigned short* W2t = W1t + 512 * HDIM;                 // [256][512]
    unsigned short* hbf = W2t + HDIM * 512;                 // [32768][256] bf16
    unsigned short* Bu  = hbf + (size_t)MTOT * HDIM;        // [32768][512] bf16 (in-place -> x)

    ln_k<<<MTOT / 4, 256, 0, stream>>>(u, hbf, gam, bet);
    wpack_k<<<2 * PDIM, HDIM, 0, stream>>>(llr, lim, ldl, Br, Bi, Cr, Ci, W1t, W2t);
    params_k<<<1, PDIM, 0, stream>>>(llr, lim, ldl, par);

    // GEMM1: Bu[32768][512] = h[32768][256] @ W1t^T   (bf16 in, bf16 out)
    mfma_gemm_k<0, HDIM><<<dim3(512 / 128, MTOT / 128), 256, 0, stream>>>(
        hbf, W1t, (void*)Bu, nullptr, 512);

    scan_reduce_k<<<dim3(NCHUNK, BATCH), PDIM, 0, stream>>>(Bu, par, last);
    scan_carry_k<<<BATCH, PDIM, 0, stream>>>(last, prefix, par);
    scan_apply_k<<<dim3(NCHUNK, BATCH), PDIM, 0, stream>>>(Bu, par, prefix);

    // GEMM2: out[32768][256] = u + gelu( x[32768][512] @ W2t^T )   (fp32 out)
    mfma_gemm_k<1, 512><<<dim3(HDIM / 128, MTOT / 128), 256, 0, stream>>>(
        Bu, W2t, (void*)out, u, HDIM);
}